// Round 6
// baseline (23.843 us; speedup 1.0000x reference)
//
#include <hip/hip_runtime.h>
#include <math.h>

#define VOCAB  100000
#define DIM    128
#define BATCH  16384
#define NEG    10
#define NBLOCK (BATCH / 8)   // 2048 blocks, 8 rows each

// Numerically stable log-sigmoid: log(1/(1+e^-x)) = min(x,0) - log1p(e^-|x|)
__device__ __forceinline__ float logsig(float x) {
    float ax = fabsf(x);
    float l  = log1pf(expf(-ax));
    return (x >= 0.0f) ? -l : (x - l);
}

// Stage 1: 32 lanes per batch row (float4/lane = 16B), 2 rows/wave, 8 rows
// per 256-thread block, 2048 blocks = 8192 waves = one fully-resident batch.
//
// R6 change: block-cooperative index staging. The block's 96 indices
// (8 rows x [10 neg + focus + ctx]) are 3 contiguous runs in memory; load
// them with 3 coalesced vmem requests into LDS instead of 56 per-group
// broadcast loads (was ~54% of the block's vmem instruction count).
__global__ __launch_bounds__(256) void sg_partial_kernel(
    const float* __restrict__ focus_W,
    const float* __restrict__ context_W,
    const int*   __restrict__ focus_idx,
    const int*   __restrict__ context_idx,
    const int*   __restrict__ neg_idx,
    float*       __restrict__ partial)
{
    const int t    = threadIdx.x;
    const int sub  = t >> 5;                 // 0..7: row-slot in block
    const int lane = t & 31;                 // lane within 32-lane row group
    const int row  = blockIdx.x * 8 + sub;

    __shared__ int s_neg[80];                // [8 rows][10]
    __shared__ int s_f[8];
    __shared__ int s_c[8];

    // Coalesced block-level index load: threads 0-79 (wave 0 + half of
    // wave 1) fetch all neg indices; 80-87 focus; 88-95 ctx. 3 requests.
    if (t < 80) {
        s_neg[t] = neg_idx[(size_t)blockIdx.x * 80 + t];
    } else if (t < 88) {
        s_f[t - 80] = focus_idx[blockIdx.x * 8 + (t - 80)];
    } else if (t < 96) {
        s_c[t - 88] = context_idx[blockIdx.x * 8 + (t - 88)];
    }
    __syncthreads();

    // Per-group broadcast reads from LDS (same address across 32 lanes).
    const int fi = s_f[sub];
    const int ci = s_c[sub];

    // lane holds elements [4*lane .. 4*lane+3] of the 128-dim embedding
    const float4 f = *(const float4*)(focus_W   + (size_t)fi * DIM + lane * 4);
    const float4 c = *(const float4*)(context_W + (size_t)ci * DIM + lane * 4);

    // neg_score = dot(focus, sum_k context_W[nk]) (einsum summed over K)
    float4 ns = make_float4(0.f, 0.f, 0.f, 0.f);
    #pragma unroll
    for (int k = 0; k < NEG; ++k) {
        const int ni = s_neg[sub * NEG + k];
        const float4 n = *(const float4*)(context_W + (size_t)ni * DIM + lane * 4);
        ns.x += n.x; ns.y += n.y; ns.z += n.z; ns.w += n.w;
    }

    float pos = f.x * c.x  + f.y * c.y  + f.z * c.z  + f.w * c.w;
    float neg = f.x * ns.x + f.y * ns.y + f.z * ns.z + f.w * ns.w;

    // 32-lane butterfly (xor offsets < 32 stay inside each row group)
    #pragma unroll
    for (int off = 16; off > 0; off >>= 1) {
        pos += __shfl_xor(pos, off);
        neg += __shfl_xor(neg, off);
    }

    if (lane == 0) {
        float pp = logsig(pos);
        float np = logsig(neg);
        partial[row] = (1.0f - pp) * (1.0f - pp) + np * np;
    }
}

// Stage 2: one 256-thread block reduces 16384 floats (64KB) -> out[0].
// 16 float4 per thread, fully unrolled independent loads.
__global__ __launch_bounds__(256) void sg_final_kernel(
    const float4* __restrict__ partial, float* __restrict__ out)
{
    const int t = threadIdx.x;
    float s = 0.0f;
    #pragma unroll
    for (int i = 0; i < 16; ++i) {
        float4 p = partial[t + i * 256];      // 4096 float4 total
        s += (p.x + p.y) + (p.z + p.w);
    }

    #pragma unroll
    for (int off = 32; off > 0; off >>= 1) s += __shfl_xor(s, off);

    __shared__ float ws[4];
    if ((t & 63) == 0) ws[t >> 6] = s;
    __syncthreads();
    if (t == 0) out[0] = (ws[0] + ws[1]) + (ws[2] + ws[3]);
}

extern "C" void kernel_launch(void* const* d_in, const int* in_sizes, int n_in,
                              void* d_out, int out_size, void* d_ws, size_t ws_size,
                              hipStream_t stream) {
    const float* focus_W     = (const float*)d_in[0];
    const float* context_W   = (const float*)d_in[1];
    const int*   focus_idx   = (const int*)d_in[2];
    const int*   context_idx = (const int*)d_in[3];
    const int*   neg_idx     = (const int*)d_in[4];
    float*       out         = (float*)d_out;
    float*       partial     = (float*)d_ws;   // 16384 floats = 64KB scratch

    sg_partial_kernel<<<NBLOCK, 256, 0, stream>>>(
        focus_W, context_W, focus_idx, context_idx, neg_idx, partial);
    sg_final_kernel<<<1, 256, 0, stream>>>((const float4*)partial, out);
}